// Round 6
// baseline (250.699 us; speedup 1.0000x reference)
//
#include <hip/hip_runtime.h>
#include <hip/hip_bf16.h>

#define NN      50000
#define INDIM   512
#define HIDDEN  256
#define NE      800000
#define BIASF   0.0001f

typedef __attribute__((ext_vector_type(4))) float  f32x4;
typedef __attribute__((ext_vector_type(4))) __bf16 bf16x4;
typedef __attribute__((ext_vector_type(8))) __bf16 bf16x8;

// async global->LDS DMA, 16 B per lane, no VGPR round-trip [m97]
__device__ __forceinline__ void async_copy16(const float* gp, float* lp) {
    __builtin_amdgcn_global_load_lds(
        (const __attribute__((address_space(1))) void*)gp,
        (__attribute__((address_space(3))) void*)lp,
        16, 0, 0);
}

// ---------------------------------------------------------------------------
// prep: blocks 0..31 : Wtb[n][k] = (bf16)W_emb[k][n] via coalesced LDS transpose
//       block  32    : w_sym[j] = 0.5*(We[j]+We[j+256])
// ---------------------------------------------------------------------------
__global__ __launch_bounds__(256) void prep_kernel(const float* __restrict__ W_emb,
                                                   const float* __restrict__ W_edge,
                                                   __bf16* __restrict__ Wtb,
                                                   float* __restrict__ w_sym) {
    const int b   = blockIdx.x;
    const int tid = threadIdx.x;
    if (b < 32) {
        __shared__ float t[64 * 65];
        const int kt = (b >> 2) * 64;
        const int nt = (b & 3) * 64;
        const int rr = tid >> 4;           // 0..15
        const int cc = (tid & 15) * 4;     // 0..60
#pragma unroll
        for (int p = 0; p < 4; ++p) {
            int r = p * 16 + rr;
            f32x4 v = *(const f32x4*)&W_emb[(size_t)(kt + r) * HIDDEN + nt + cc];
            t[(cc + 0) * 65 + r] = v[0];
            t[(cc + 1) * 65 + r] = v[1];
            t[(cc + 2) * 65 + r] = v[2];
            t[(cc + 3) * 65 + r] = v[3];
        }
        __syncthreads();
#pragma unroll
        for (int p = 0; p < 4; ++p) {
            int n = p * 16 + rr;
            bf16x4 o;
            o[0] = (__bf16)t[n * 65 + cc + 0];
            o[1] = (__bf16)t[n * 65 + cc + 1];
            o[2] = (__bf16)t[n * 65 + cc + 2];
            o[3] = (__bf16)t[n * 65 + cc + 3];
            *(bf16x4*)&Wtb[(size_t)(nt + n) * INDIM + kt + cc] = o;
        }
    } else {
        w_sym[tid] = 0.5f * (W_edge[tid] + W_edge[tid + HIDDEN]);
    }
}

// ---------------------------------------------------------------------------
// BM=16 stream GEMM + fused node-dot (NN = 3125 * 16, zero tail):
//   g[m] = sum_n relu(emb[m]@W[:,n] + b[n]) * w_sym[n]
// Per block: stage 16 rows x full K=512 fp32 (32 KB, one contiguous 32 KB
// global span) via global_load_lds width=16, ONE barrier, then a barrier-free
// 16-kstep MFMA loop. LDS 33 KB -> 4 blocks/CU, 16 waves/CU: 4 resident
// blocks at staggered phases keep the DMA pipe busy while others compute.
// 4 waves split N into 64-col quarters (4 MFMA N-tiles each, M-tile = 16).
// B: bf16x8 fragments direct from the 256 KB L2-hot Wtb, immediate offsets.
// fp32->bf16 cvt at fragment read, hidden under MFMA.
// ---------------------------------------------------------------------------
__global__ __launch_bounds__(256, 4) void gemm_g_kernel(const float* __restrict__ A,
                                                        const __bf16* __restrict__ Wtb,
                                                        const float* __restrict__ bias,
                                                        const float* __restrict__ w_sym,
                                                        float* __restrict__ g) {
    constexpr int LDA = 516;                     // f32 per LDS row (512 + 4 pad)
    __shared__ __align__(16) float As[16 * LDA]; // 33,024 B
    __shared__ float red[4][16];

    const int tid  = threadIdx.x;
    const int lane = tid & 63;
    const int w    = tid >> 6;                   // wave id = N-quarter
    const int ml   = lane & 15, kq = lane >> 4;
    const int m0   = blockIdx.x * 16;

    // ---- async stage: 4 rows per wave x 2 K-halves = 8 x 1 KB DMA ----
#pragma unroll
    for (int j = 0; j < 8; ++j) {
        int r = w * 4 + (j >> 1);                // row 0..15
        int h = j & 1;                           // K-half
        const float* gp = A + (size_t)(m0 + r) * INDIM + h * 256 + lane * 4;
        async_copy16(gp, &As[r * LDA + h * 256]);
    }

    const __bf16* bp[4];
#pragma unroll
    for (int nt = 0; nt < 4; ++nt) {
        int col = w * 64 + nt * 16 + ml;
        bp[nt] = Wtb + (size_t)col * INDIM + kq * 8;
    }

    f32x4 acc[4];
#pragma unroll
    for (int nt = 0; nt < 4; ++nt) acc[nt] = (f32x4)0.0f;

    __syncthreads();                             // drains vmcnt -> DMA complete

    // ---- barrier-free K-loop: 16 ksteps of K=32 ----
#pragma unroll
    for (int ks = 0; ks < 16; ++ks) {
        const float* lf = &As[ml * LDA + ks * 32 + kq * 8];
        f32x4 lo = *(const f32x4*)lf;
        f32x4 hi = *(const f32x4*)(lf + 4);
        bf16x8 af;
        af[0] = (__bf16)lo[0]; af[1] = (__bf16)lo[1];
        af[2] = (__bf16)lo[2]; af[3] = (__bf16)lo[3];
        af[4] = (__bf16)hi[0]; af[5] = (__bf16)hi[1];
        af[6] = (__bf16)hi[2]; af[7] = (__bf16)hi[3];
        bf16x8 bfr[4];
#pragma unroll
        for (int nt = 0; nt < 4; ++nt)
            bfr[nt] = *(const bf16x8*)(bp[nt] + ks * 32);
#pragma unroll
        for (int nt = 0; nt < 4; ++nt)
            acc[nt] = __builtin_amdgcn_mfma_f32_16x16x32_bf16(
                af, bfr[nt], acc[nt], 0, 0, 0);
    }

    // ---- epilogue: relu + dot w_sym, xor-reduce over the 16 ml lanes,
    //      cross-wave sum via tiny LDS. C/D: col=ml, row=kq*4+reg [m89/m91] ----
    float wsv[4], bcv[4];
#pragma unroll
    for (int nt = 0; nt < 4; ++nt) {
        int col = w * 64 + nt * 16 + ml;
        wsv[nt] = w_sym[col];
        bcv[nt] = bias[col];
    }
#pragma unroll
    for (int r = 0; r < 4; ++r) {
        float s = 0.0f;
#pragma unroll
        for (int nt = 0; nt < 4; ++nt) {
            float x = acc[nt][r] + bcv[nt];
            s = fmaf(fmaxf(x, 0.0f), wsv[nt], s);
        }
        s += __shfl_xor(s, 1);
        s += __shfl_xor(s, 2);
        s += __shfl_xor(s, 4);
        s += __shfl_xor(s, 8);
        if (ml == 0) red[w][kq * 4 + r] = s;
    }
    __syncthreads();
    if (tid < 16)
        g[m0 + tid] = red[0][tid] + red[1][tid] + red[2][tid] + red[3][tid];
}

// ---------------------------------------------------------------------------
// edge kernel: one THREAD per edge; g gathers are 4B hits in a 200 KB array.
// ---------------------------------------------------------------------------
__global__ __launch_bounds__(256) void edge_kernel(const float* __restrict__ g,
                                                   const int* __restrict__ edges,
                                                   const float* __restrict__ u,
                                                   const float* __restrict__ b_edge,
                                                   float* __restrict__ out) {
    const int e  = blockIdx.x * 256 + threadIdx.x;      // NE = 3125*256 exactly
    const int i0 = edges[e];
    const int i1 = edges[NE + e];
    float raw = g[i0] + g[i1] + b_edge[0];
    float uu  = u[e];
    float eps = fmaf(uu, BIASF - (1.0f - BIASF), 1.0f - BIASF); // -0.9998u+0.9999
    float gt  = logf(eps) - log1pf(-eps) + raw;                 // TEMPERATURE=1
    out[e] = 1.0f / (1.0f + expf(-gt));
}

// ---------------------------------------------------------------------------
extern "C" void kernel_launch(void* const* d_in, const int* in_sizes, int n_in,
                              void* d_out, int out_size, void* d_ws, size_t ws_size,
                              hipStream_t stream) {
    const float* embedding = (const float*)d_in[0];
    const int*   edges     = (const int*)d_in[1];
    const float* u         = (const float*)d_in[2];
    const float* W_emb     = (const float*)d_in[3];
    const float* b_emb     = (const float*)d_in[4];
    const float* W_edge    = (const float*)d_in[5];
    const float* b_edge    = (const float*)d_in[6];
    float*       out       = (float*)d_out;

    // workspace layout
    char*   ws    = (char*)d_ws;
    __bf16* Wtb   = (__bf16*)ws;                      // 262,144 B
    float*  w_sym = (float*)(ws + 262144);            //   1,024 B
    float*  g     = (float*)(ws + 262144 + 1024);     // 200,000 B

    prep_kernel<<<33, 256, 0, stream>>>(W_emb, W_edge, Wtb, w_sym);

    gemm_g_kernel<<<3125, 256, 0, stream>>>(embedding, Wtb, b_emb, w_sym, g);

    edge_kernel<<<NE / 256, 256, 0, stream>>>(g, edges, u, b_edge, out);
}

// Round 7
// 212.794 us; speedup vs baseline: 1.1781x; 1.1781x over previous
//
#include <hip/hip_runtime.h>
#include <hip/hip_bf16.h>

#define NN      50000
#define INDIM   512
#define HIDDEN  256
#define NE      800000
#define BIASF   0.0001f

typedef __attribute__((ext_vector_type(4))) float  f32x4;
typedef __attribute__((ext_vector_type(4))) __bf16 bf16x4;
typedef __attribute__((ext_vector_type(8))) __bf16 bf16x8;

// async global->LDS DMA, 16 B per lane, no VGPR round-trip [m97]
__device__ __forceinline__ void async_copy16(const float* gp, float* lp) {
    __builtin_amdgcn_global_load_lds(
        (const __attribute__((address_space(1))) void*)gp,
        (__attribute__((address_space(3))) void*)lp,
        16, 0, 0);
}

// ---------------------------------------------------------------------------
// prep: blocks 0..31 : Wtb[n][k] = (bf16)W_emb[k][n] via coalesced LDS transpose
//       block  32    : w_sym[j] = 0.5*(We[j]+We[j+256])
// ---------------------------------------------------------------------------
__global__ __launch_bounds__(256) void prep_kernel(const float* __restrict__ W_emb,
                                                   const float* __restrict__ W_edge,
                                                   __bf16* __restrict__ Wtb,
                                                   float* __restrict__ w_sym) {
    const int b   = blockIdx.x;
    const int tid = threadIdx.x;
    if (b < 32) {
        __shared__ float t[64 * 65];
        const int kt = (b >> 2) * 64;
        const int nt = (b & 3) * 64;
        const int rr = tid >> 4;           // 0..15
        const int cc = (tid & 15) * 4;     // 0..60
#pragma unroll
        for (int p = 0; p < 4; ++p) {
            int r = p * 16 + rr;
            f32x4 v = *(const f32x4*)&W_emb[(size_t)(kt + r) * HIDDEN + nt + cc];
            t[(cc + 0) * 65 + r] = v[0];
            t[(cc + 1) * 65 + r] = v[1];
            t[(cc + 2) * 65 + r] = v[2];
            t[(cc + 3) * 65 + r] = v[3];
        }
        __syncthreads();
#pragma unroll
        for (int p = 0; p < 4; ++p) {
            int n = p * 16 + rr;
            bf16x4 o;
            o[0] = (__bf16)t[n * 65 + cc + 0];
            o[1] = (__bf16)t[n * 65 + cc + 1];
            o[2] = (__bf16)t[n * 65 + cc + 2];
            o[3] = (__bf16)t[n * 65 + cc + 3];
            *(bf16x4*)&Wtb[(size_t)(nt + n) * INDIM + kt + cc] = o;
        }
    } else {
        w_sym[tid] = 0.5f * (W_edge[tid] + W_edge[tid + HIDDEN]);
    }
}

// ---------------------------------------------------------------------------
// BM=32 stream GEMM + fused node-dot:
//   g[m] = sum_n relu(emb[m]@W[:,n] + b[n]) * w_sym[n]
// r5 structure halved: 32 rows/block, K in two 256-float halves, one 1 KB
// full-width DMA per row (global_load_lds width=16). LDS 33.8 KB -> 4
// blocks/CU (16 waves/CU): four resident blocks at drifting phases overlap
// one block's DMA drain with the others' compute (the r5 66.5 KB version had
// only 2 blocks/CU and serialized DMA + compute).
// 4 waves split N into 64-col quarters; wave tile 32x64 = 2x4 MFMA tiles ->
// per K=32: 4 ds_read_b128 + 4 B-loads + 8 MFMAs (keeps r5's healthy ratio,
// unlike r6's 1:1). B: bf16x8 direct from the 256 KB L2-hot Wtb.
// ---------------------------------------------------------------------------
__global__ __launch_bounds__(256, 4) void gemm_g_kernel(const float* __restrict__ A,
                                                        const __bf16* __restrict__ Wtb,
                                                        const float* __restrict__ bias,
                                                        const float* __restrict__ w_sym,
                                                        float* __restrict__ g) {
    constexpr int LDA = 260;                     // f32 per LDS row (256 + 4 pad)
    __shared__ __align__(16) float As[32 * LDA]; // 33,280 B
    __shared__ float red[4][32];

    const int tid  = threadIdx.x;
    const int lane = tid & 63;
    const int w    = tid >> 6;                   // wave id = N-quarter
    const int ml   = lane & 15, kq = lane >> 4;
    const int m0   = blockIdx.x * 32;

    f32x4 acc[2][4];
#pragma unroll
    for (int mt = 0; mt < 2; ++mt)
#pragma unroll
        for (int nt = 0; nt < 4; ++nt) acc[mt][nt] = (f32x4)0.0f;

    const __bf16* bp[4];
#pragma unroll
    for (int nt = 0; nt < 4; ++nt) {
        int col = w * 64 + nt * 16 + ml;
        bp[nt] = Wtb + (size_t)col * INDIM + kq * 8;
    }

#pragma unroll
    for (int h = 0; h < 2; ++h) {
        if (h) __syncthreads();                  // all waves done reading half 0
        // ---- async stage: 8 rows per wave, one 1 KB DMA per row ----
#pragma unroll
        for (int j = 0; j < 8; ++j) {
            int r  = w * 8 + j;                  // row 0..31
            int gr = m0 + r; if (gr > NN - 1) gr = NN - 1;   // M-tail clamp
            const float* gp = A + (size_t)gr * INDIM + h * 256 + lane * 4;
            async_copy16(gp, &As[r * LDA]);
        }
        __syncthreads();                         // drains vmcnt -> DMA complete

        // ---- barrier-free K-loop: 8 ksteps of K=32 ----
#pragma unroll
        for (int ks = 0; ks < 8; ++ks) {
            bf16x8 af[2], bfr[4];
#pragma unroll
            for (int mt = 0; mt < 2; ++mt) {
                const float* lf = &As[(mt * 16 + ml) * LDA + ks * 32 + kq * 8];
                f32x4 lo = *(const f32x4*)lf;
                f32x4 hi = *(const f32x4*)(lf + 4);
                af[mt][0] = (__bf16)lo[0]; af[mt][1] = (__bf16)lo[1];
                af[mt][2] = (__bf16)lo[2]; af[mt][3] = (__bf16)lo[3];
                af[mt][4] = (__bf16)hi[0]; af[mt][5] = (__bf16)hi[1];
                af[mt][6] = (__bf16)hi[2]; af[mt][7] = (__bf16)hi[3];
            }
#pragma unroll
            for (int nt = 0; nt < 4; ++nt)
                bfr[nt] = *(const bf16x8*)(bp[nt] + h * 256 + ks * 32);
#pragma unroll
            for (int mt = 0; mt < 2; ++mt)
#pragma unroll
                for (int nt = 0; nt < 4; ++nt)
                    acc[mt][nt] = __builtin_amdgcn_mfma_f32_16x16x32_bf16(
                        af[mt], bfr[nt], acc[mt][nt], 0, 0, 0);
        }
    }

    // ---- epilogue: relu+dot w_sym, xor-reduce over ml lanes, cross-wave LDS ----
    // C/D layout: col = ml, row = kq*4 + reg  [verified m89/m91]
    float wsv[4], bcv[4];
#pragma unroll
    for (int nt = 0; nt < 4; ++nt) {
        int col = w * 64 + nt * 16 + ml;
        wsv[nt] = w_sym[col];
        bcv[nt] = bias[col];
    }
#pragma unroll
    for (int mt = 0; mt < 2; ++mt) {
#pragma unroll
        for (int r = 0; r < 4; ++r) {
            float s = 0.0f;
#pragma unroll
            for (int nt = 0; nt < 4; ++nt) {
                float x = acc[mt][nt][r] + bcv[nt];
                s = fmaf(fmaxf(x, 0.0f), wsv[nt], s);
            }
            s += __shfl_xor(s, 1);
            s += __shfl_xor(s, 2);
            s += __shfl_xor(s, 4);
            s += __shfl_xor(s, 8);
            if (ml == 0) red[w][mt * 16 + kq * 4 + r] = s;
        }
    }
    __syncthreads();
    if (tid < 32) {
        int row = m0 + tid;
        if (row < NN)
            g[row] = red[0][tid] + red[1][tid] + red[2][tid] + red[3][tid];
    }
}

// ---------------------------------------------------------------------------
// edge kernel: one THREAD per edge; g gathers are 4B hits in a 200 KB array.
// ---------------------------------------------------------------------------
__global__ __launch_bounds__(256) void edge_kernel(const float* __restrict__ g,
                                                   const int* __restrict__ edges,
                                                   const float* __restrict__ u,
                                                   const float* __restrict__ b_edge,
                                                   float* __restrict__ out) {
    const int e  = blockIdx.x * 256 + threadIdx.x;      // NE = 3125*256 exactly
    const int i0 = edges[e];
    const int i1 = edges[NE + e];
    float raw = g[i0] + g[i1] + b_edge[0];
    float uu  = u[e];
    float eps = fmaf(uu, BIASF - (1.0f - BIASF), 1.0f - BIASF); // -0.9998u+0.9999
    float gt  = logf(eps) - log1pf(-eps) + raw;                 // TEMPERATURE=1
    out[e] = 1.0f / (1.0f + expf(-gt));
}

// ---------------------------------------------------------------------------
extern "C" void kernel_launch(void* const* d_in, const int* in_sizes, int n_in,
                              void* d_out, int out_size, void* d_ws, size_t ws_size,
                              hipStream_t stream) {
    const float* embedding = (const float*)d_in[0];
    const int*   edges     = (const int*)d_in[1];
    const float* u         = (const float*)d_in[2];
    const float* W_emb     = (const float*)d_in[3];
    const float* b_emb     = (const float*)d_in[4];
    const float* W_edge    = (const float*)d_in[5];
    const float* b_edge    = (const float*)d_in[6];
    float*       out       = (float*)d_out;

    // workspace layout
    char*   ws    = (char*)d_ws;
    __bf16* Wtb   = (__bf16*)ws;                      // 262,144 B
    float*  w_sym = (float*)(ws + 262144);            //   1,024 B
    float*  g     = (float*)(ws + 262144 + 1024);     // 200,000 B

    prep_kernel<<<33, 256, 0, stream>>>(W_emb, W_edge, Wtb, w_sym);

    gemm_g_kernel<<<1563, 256, 0, stream>>>(embedding, Wtb, b_emb, w_sym, g);

    edge_kernel<<<NE / 256, 256, 0, stream>>>(g, edges, u, b_edge, out);
}